// Round 1
// 238095.215 us; speedup vs baseline: 3.4533x; 3.4533x over previous
//
#include <hip/hip_runtime.h>

typedef unsigned short u16;
typedef unsigned int   u32;

// ---------------- problem constants ----------------
#define NB 256
#define NT 512
#define TSTEPS 401
#define GATE_OFF   19709952   // 401*32*1536

// ws offsets (floats). Natural orientations, f32 everywhere except H2B
// (bf16 internal cache). Total 6,013,248 floats = 24.05 MiB.
#define OFF_ATTH    64        // 2 par * 4096
#define OFF_ATTC    8256      // 4096
#define OFF_DECH    12352     // 2 par * 32768
#define OFF_DECC    77888     // 32768
#define OFF_CTX     110656    // 16384
#define OFF_AW      127040    // 16384
#define OFF_AWC     143424    // 16384
#define OFF_PSUM    159808    // 256
#define OFF_E       160064    // 16384 -> 176448
#define OFF_LOCA    176448    // f32 [32][512][128] -> 2273600
#define OFF_WENC    2273600   // f32 [32][512][128] -> 4370752
#define OFF_H2B     4370752   // u16 [12832][256] = 1642496 floats -> 6013248
#define NEED_BYTES  24052992
#define ZERO_BYTES  (OFF_PSUM * 4)

#define LOG2E 1.44269504088896340736f
#define RELFLAG 32            // release flag 128B away from arrival counter

struct KParams {
    const void *enc, *mel, *pw1, *pb1, *pw2, *pb2, *awx, *awh, *ab, *wq,
               *wmem, *convw, *wloc, *vv, *dwx, *dwh, *db, *gw, *gb;
    float* ws;
    float* out;    // OUTPUT IS FLOAT32 (reference returns jnp.float32)
};

__device__ __forceinline__ float bf2f(u16 h) {
    return __uint_as_float(((u32)h) << 16);
}
__device__ __forceinline__ u16 f2bf(float f) {
    u32 u = __float_as_uint(f);
    u32 lsb = (u >> 16) & 1u;
    u += 0x7fffu + lsb;
    return (u16)(u >> 16);
}
template<bool F32>
__device__ __forceinline__ float LD(const void* q, int i) {
    if (F32) return ((const float*)q)[i];
    return bf2f(((const u16*)q)[i]);
}
__device__ __forceinline__ float fexp2_(float x) { return __builtin_amdgcn_exp2f(x); }
__device__ __forceinline__ float frcp_(float x)  { return __builtin_amdgcn_rcpf(x); }
__device__ __forceinline__ float sigm_(float x) {
    return frcp_(1.0f + fexp2_(-LOG2E * x));
}
__device__ __forceinline__ float tanh_(float x) {
    float e = fexp2_(2.0f * LOG2E * x);
    return 1.0f - 2.0f * frcp_(e + 1.0f);
}

// Coherent (agent-scope, relaxed) accessors for cross-block state.
// These bypass non-coherent L1/L2 WITHOUT cache-wide invalidates, so
// read-only data (weights/enc) stays resident in L2 across steps.
// RULE: a location written with CS must ALWAYS be read with CL.
__device__ __forceinline__ float CL(const float* p) {
    return __hip_atomic_load(p, __ATOMIC_RELAXED, __HIP_MEMORY_SCOPE_AGENT);
}
__device__ __forceinline__ void CS(float* p, float v) {
    __hip_atomic_store(p, v, __ATOMIC_RELAXED, __HIP_MEMORY_SCOPE_AGENT);
}

// grid barrier: monotone generation counter.
// FULL=true : acq_rel arrival + acquire polls (whole-cache fences) — used
//             ONCE after precompute so plain-written H2B/WENC become visible.
// FULL=false: fully relaxed. Data correctness comes from (a) __syncthreads
//             draining vmcnt(0) so all coherent stores are globally visible
//             before the arrival add, (b) all cross-block state using CL/CS.
//             Hedge: every 4096 spins poll with acquire (deadlock insurance).
template<bool FULL>
__device__ __forceinline__ void gbar(u32* bar, u32* genp) {
    __syncthreads();
    if (threadIdx.x == 0) {
        u32 g = ++(*genp);
        u32 prev = __hip_atomic_fetch_add(&bar[0], 1u,
            FULL ? __ATOMIC_ACQ_REL : __ATOMIC_RELAXED, __HIP_MEMORY_SCOPE_AGENT);
        if (prev + 1u == g * (u32)NB) {
            __hip_atomic_store(&bar[RELFLAG], g,
                FULL ? __ATOMIC_RELEASE : __ATOMIC_RELAXED, __HIP_MEMORY_SCOPE_AGENT);
        } else {
            u32 r, n = 0;
            for (;;) {
                __builtin_amdgcn_s_sleep(8);
                if (FULL || ((++n & 4095u) == 0u))
                    r = __hip_atomic_load(&bar[RELFLAG], __ATOMIC_ACQUIRE,
                                          __HIP_MEMORY_SCOPE_AGENT);
                else
                    r = __hip_atomic_load(&bar[RELFLAG], __ATOMIC_RELAXED,
                                          __HIP_MEMORY_SCOPE_AGENT);
                if (r >= g) break;
            }
        }
    }
    __syncthreads();
}

template<bool F32>
__device__ void decoder_body(const KParams& p, float* sm, u32* genp) {
    const int tid = threadIdx.x;
    const int blk = blockIdx.x;
    float* ws = p.ws;
    u32* bar = (u32*)ws;
    u16* h2b = (u16*)(ws + OFF_H2B);
    float* outp = p.out;

    // ============ precompute 1: H2[r][c] = prenet(mel row r), r = t*32+b ============
    for (int r = blk; r < 12832; r += NB) {
        const int t = r >> 5, b = r & 31;
        if (tid < 80)
            sm[tid] = (t > 0) ? LD<F32>(p.mel, b * 32000 + (t - 1) * 80 + tid) : 0.0f;
        __syncthreads();
        if (tid < 256) {
            float a = LD<F32>(p.pb1, tid);
            for (int k = 0; k < 80; ++k) a += sm[k] * LD<F32>(p.pw1, k * 256 + tid);
            sm[96 + tid] = a > 0.f ? a : 0.f;
        }
        __syncthreads();
        if (tid < 256) {
            float a = LD<F32>(p.pb2, tid);
            for (int k = 0; k < 256; ++k) a += sm[96 + k] * LD<F32>(p.pw2, k * 256 + tid);
            h2b[r * 256 + tid] = f2bf(a > 0.f ? a : 0.f);
        }
        __syncthreads();
    }
    // ============ precompute 2: WENC[b][te][a] = sum_k enc[b][te][k]*Wmem[k][a] ============
    for (int r = blk; r < 16384; r += NB) {
        const int b = r >> 9, te = r & 511;
        sm[tid] = LD<F32>(p.enc, b * 262144 + te * 512 + tid);
        __syncthreads();
        if (tid < 128) {
            float a = 0.0f;
            for (int k = 0; k < 512; ++k) a += sm[k] * LD<F32>(p.wmem, k * 128 + tid);
            ws[OFF_WENC + r * 128 + tid] = a;
        }
        __syncthreads();
    }
    gbar<true>(bar, genp);   // the ONLY full-fence barrier: publishes H2B/WENC

    // ======================= scan over 401 steps =======================
    for (int t = 0; t < TSTEPS; ++t) {
        const int pn = t & 1, po = pn ^ 1;

        // ---------- Phase 0: att LSTM | conv+loc | gate(t-1) ----------
        if (blk < 32) {
            // attention LSTM, one block per batch b
            const int b = blk;
            for (int i = tid; i < 896; i += NT) {
                float v;
                if (i < 256)      v = bf2f(h2b[(t * 32 + b) * 256 + i]);
                else if (i < 768) v = CL(ws + OFF_CTX + b * 512 + (i - 256));
                else              v = CL(ws + OFF_ATTH + po * 4096 + b * 128 + (i - 768));
                sm[i] = v;
            }
            __syncthreads();
            {
                const int j = tid;  // column in [0,512)
                float z = LD<F32>(p.ab, j);
#pragma unroll 8
                for (int k = 0; k < 768; ++k) z += sm[k] * LD<F32>(p.awx, k * 512 + j);
#pragma unroll 8
                for (int k = 0; k < 128; ++k) z += sm[768 + k] * LD<F32>(p.awh, k * 512 + j);
                sm[896 + j] = z;
            }
            __syncthreads();
            if (tid < 128) {
                const int u = tid;
                float zi = sm[896 + u];
                float zf = sm[896 + 128 + u];
                float zg = sm[896 + 256 + u];
                float zo = sm[896 + 384 + u];
                float co = ws[OFF_ATTC + b * 128 + u];          // private, plain
                float cn = sigm_(zf) * co + sigm_(zi) * tanh_(zg);
                float hn = sigm_(zo) * tanh_(cn);
                ws[OFF_ATTC + b * 128 + u] = cn;                // private, plain
                CS(ws + OFF_ATTH + pn * 4096 + b * 128 + u, hn);
            }
        } else if (blk < 96) {
            // location conv + @Wloc + WENC -> LOCA[b][te][a]; 2 blocks per batch
            const int idx = blk - 32, b = idx >> 1, th = idx & 1, te0 = th * 256;
            float* CONVL = sm + 572;   // [32][256]
            for (int i = tid; i < 286; i += NT) {
                int te = te0 - 15 + i;
                bool ok = (te >= 0) && (te < 512);
                sm[i]       = ok ? CL(ws + OFF_AW + b * 512 + te) : 0.0f;
                sm[286 + i] = ok ? CL(ws + OFF_AWC + b * 512 + te) : 0.0f;
            }
            __syncthreads();
            {
                const int te_l = tid & 255, rf = tid >> 8;
                for (int ff = 0; ff < 16; ++ff) {
                    const int f = rf * 16 + ff;
                    float acc = 0.0f;
#pragma unroll
                    for (int k = 0; k < 31; ++k)
                        acc += sm[te_l + k] * LD<F32>(p.convw, k * 64 + f)
                             + sm[286 + te_l + k] * LD<F32>(p.convw, k * 64 + 32 + f);
                    CONVL[f * 256 + te_l] = acc;
                }
            }
            __syncthreads();
            {
                // lane-major over 'a': coalesced WENC reads + coalesced LOCA
                // coherent stores; wloc hoisted to registers (reused over te).
                const int a_l = tid & 127, tg = tid >> 7;   // tg in [0,4)
                float wl[32];
#pragma unroll
                for (int f = 0; f < 32; ++f) wl[f] = LD<F32>(p.wloc, f * 128 + a_l);
                for (int te_i = tg * 64; te_i < tg * 64 + 64; ++te_i) {
                    const int te = te0 + te_i;
                    float acc = ws[OFF_WENC + (b * 512 + te) * 128 + a_l];  // RO, plain
#pragma unroll 8
                    for (int f = 0; f < 32; ++f) acc += CONVL[f * 256 + te_i] * wl[f];
                    CS(ws + OFF_LOCA + (b * 512 + te) * 128 + a_l, acc);
                }
            }
        } else if (blk < 128) {
            // gate(t-1): uses dec_h(t-1)=DECH[po] and ctx(t-1)=CTX (not yet overwritten)
            if (t > 0) {
                const int b = blk - 96;
                const float* dh = ws + OFF_DECH + po * 32768 + b * 1024;
                float pg = CL(dh + tid) * LD<F32>(p.gw, tid)
                         + CL(dh + 512 + tid) * LD<F32>(p.gw, 512 + tid)
                         + CL(ws + OFF_CTX + b * 512 + tid) * LD<F32>(p.gw, 1024 + tid);
#pragma unroll
                for (int o = 32; o > 0; o >>= 1) pg += __shfl_down(pg, o, 64);
                if ((tid & 63) == 0) sm[tid >> 6] = pg;
                __syncthreads();
                if (tid == 0) {
                    float s = LD<F32>(p.gb, 0);
#pragma unroll
                    for (int w = 0; w < 8; ++w) s += sm[w];
                    outp[GATE_OFF + (t - 1) * 32 + b] = s;
                }
            }
        }
        gbar<false>(bar, genp);

        // ---------- Phase 1: energies -> exp, per-chunk partial sums ----------
        {
            const int b = blk >> 3, tc = blk & 7, te0 = tc * 64;
            if (tid < 128) {
                sm[512 + tid] = CL(ws + OFF_ATTH + pn * 4096 + b * 128 + tid);
                sm[128 + tid] = LD<F32>(p.vv, tid);
            }
            __syncthreads();
            if (tid < 128) {
                float pq = 0.0f;
#pragma unroll 8
                for (int k = 0; k < 128; ++k)
                    pq += sm[512 + k] * LD<F32>(p.wq, k * 128 + tid);
                sm[tid] = pq;
            }
            __syncthreads();
            {
                const int te_l = tid >> 3, ag = tid & 7;
                const int te = te0 + te_l;
                const float* lb = ws + OFF_LOCA + (b * 512 + te) * 128;
                float part = 0.0f;
#pragma unroll 8
                for (int aa = 0; aa < 16; ++aa) {
                    int a = ag * 16 + aa;
                    part += tanh_(CL(lb + a) + sm[a]) * sm[128 + a];
                }
                sm[256 + te_l * 8 + ag] = part;
            }
            __syncthreads();
            if (tid < 64) {
                float e = 0.0f;
#pragma unroll
                for (int ag = 0; ag < 8; ++ag) e += sm[256 + tid * 8 + ag];
                float ex = fexp2_(LOG2E * e);
                CS(ws + OFF_E + b * 512 + te0 + tid, ex);
#pragma unroll
                for (int o = 32; o > 0; o >>= 1) ex += __shfl_down(ex, o, 64);
                if (tid == 0) CS(ws + OFF_PSUM + b * 8 + tc, ex);
            }
        }
        gbar<false>(bar, genp);

        // ---------- Phase 2: softmax normalize + aw/awc + context ----------
        {
            const int b = blk >> 3, dc = blk & 7, d0 = dc * 64;
            float den = 0.0f;
#pragma unroll
            for (int i = 0; i < 8; ++i) den += CL(ws + OFF_PSUM + b * 8 + i);
            const float rden = frcp_(den);
            sm[tid] = CL(ws + OFF_E + b * 512 + tid);
            __syncthreads();
            if (dc == 0) {
                float awv = sm[tid] * rden;
                CS(ws + OFF_AW + b * 512 + tid, awv);
                CS(ws + OFF_AWC + b * 512 + tid,
                   CL(ws + OFF_AWC + b * 512 + tid) + awv);
            }
            {
                const int tg = tid >> 6, d = tid & 63;
                float part = 0.0f;
#pragma unroll 8
                for (int tt = 0; tt < 64; ++tt) {
                    int te = tg * 64 + tt;
                    part += sm[te] * LD<F32>(p.enc, b * 262144 + te * 512 + d0 + d);
                }
                sm[512 + tg * 64 + d] = part;
            }
            __syncthreads();
            if (tid < 64) {
                float cr = 0.0f;
#pragma unroll
                for (int tg = 0; tg < 8; ++tg) cr += sm[512 + tg * 64 + tid];
                float cv = cr * rden;
                int d = d0 + tid;
                CS(ws + OFF_CTX + b * 512 + d, cv);
                outp[t * 49152 + b * 1536 + 1024 + d] = cv;
            }
        }
        gbar<false>(bar, genp);

        // ---------- Phase 3: decoder LSTM, 8 blocks per batch ----------
        {
            const int b = blk >> 3, jc = blk & 7;
            for (int i = tid; i < 1664; i += NT) {
                float v;
                if (i < 128)      v = CL(ws + OFF_ATTH + pn * 4096 + b * 128 + i);
                else if (i < 640) v = CL(ws + OFF_CTX + b * 512 + (i - 128));
                else              v = CL(ws + OFF_DECH + po * 32768 + b * 1024 + (i - 640));
                sm[i] = v;
            }
            __syncthreads();
            {
                const int g = tid >> 7, ul = tid & 127;
                const int j = g * 1024 + jc * 128 + ul;
                float z = LD<F32>(p.db, j);
#pragma unroll 8
                for (int k = 0; k < 640; ++k) z += sm[k] * LD<F32>(p.dwx, k * 4096 + j);
#pragma unroll 8
                for (int k = 0; k < 1024; ++k) z += sm[640 + k] * LD<F32>(p.dwh, k * 4096 + j);
                sm[1664 + tid] = z;   // [g][ul]
            }
            __syncthreads();
            if (tid < 128) {
                const int u = jc * 128 + tid;
                float zi = sm[1664 + tid];
                float zf = sm[1664 + 128 + tid];
                float zg = sm[1664 + 256 + tid];
                float zo = sm[1664 + 384 + tid];
                float co = ws[OFF_DECC + b * 1024 + u];          // private, plain
                float cn = sigm_(zf) * co + sigm_(zi) * tanh_(zg);
                float hn = sigm_(zo) * tanh_(cn);
                ws[OFF_DECC + b * 1024 + u] = cn;                // private, plain
                CS(ws + OFF_DECH + pn * 32768 + b * 1024 + u, hn);
                outp[t * 49152 + b * 1536 + u] = hn;
            }
        }
        gbar<false>(bar, genp);
    }

    // ------------- epilogue: gate(400); dec_h(400) parity = 0, CTX = ctx(400) -------------
    if (blk < 32) {
        const int b = blk;
        const float* dh = ws + OFF_DECH + 0 * 32768 + b * 1024;
        float pg = CL(dh + tid) * LD<F32>(p.gw, tid)
                 + CL(dh + 512 + tid) * LD<F32>(p.gw, 512 + tid)
                 + CL(ws + OFF_CTX + b * 512 + tid) * LD<F32>(p.gw, 1024 + tid);
#pragma unroll
        for (int o = 32; o > 0; o >>= 1) pg += __shfl_down(pg, o, 64);
        if ((tid & 63) == 0) sm[tid >> 6] = pg;
        __syncthreads();
        if (tid == 0) {
            float s = LD<F32>(p.gb, 0);
#pragma unroll
            for (int w = 0; w < 8; ++w) s += sm[w];
            outp[GATE_OFF + 400 * 32 + b] = s;
        }
    }
}

// dtype probe: enc_out ~ N(0,1). bf16 stream: even u16s are bf16 values
// (plausible exponent ~always). f32 stream: even u16s are low-mantissa words
// (uniform; plausible ~9%). Threshold 48/64 never misclassifies.
__device__ __forceinline__ bool probe_f32(const void* enc) {
    const u16* e = (const u16*)enc;
    int cnt = 0;
    for (int i = 0; i < 64; ++i) {
        u16 v = e[2 * i];
        int ex = (v >> 7) & 0xFF;
        if (ex >= 112 && ex <= 135) ++cnt;
    }
    return cnt < 48;
}

__global__ __launch_bounds__(NT) void tts_decoder(KParams p) {
    __shared__ float sm[9216];   // 36 KiB multi-purpose
    __shared__ u32 gen_sh;
    __shared__ int flag_sh;
    if (threadIdx.x == 0) {
        gen_sh = 0;
        flag_sh = probe_f32(p.enc) ? 1 : 0;
    }
    __syncthreads();
    if (flag_sh) decoder_body<true>(p, sm, &gen_sh);
    else         decoder_body<false>(p, sm, &gen_sh);
}

// sentinel: ws too small for this layout -> absmax ~12345 tells us next round
__global__ void ws_too_small(float* out) {
    if (threadIdx.x == 0 && blockIdx.x == 0) out[0] = 12345.0f;
}

extern "C" void kernel_launch(void* const* d_in, const int* in_sizes, int n_in,
                              void* d_out, int out_size, void* d_ws, size_t ws_size,
                              hipStream_t stream) {
    (void)in_sizes; (void)n_in; (void)out_size;
    if (ws_size < (size_t)NEED_BYTES) {
        ws_too_small<<<dim3(1), dim3(64), 0, stream>>>((float*)d_out);
        return;
    }
    KParams p;
    p.enc   = d_in[0];
    p.mel   = d_in[1];
    p.pw1   = d_in[2];
    p.pb1   = d_in[3];
    p.pw2   = d_in[4];
    p.pb2   = d_in[5];
    p.awx   = d_in[6];
    p.awh   = d_in[7];
    p.ab    = d_in[8];
    p.wq    = d_in[9];
    p.wmem  = d_in[10];
    p.convw = d_in[11];
    p.wloc  = d_in[12];
    p.vv    = d_in[13];
    p.dwx   = d_in[14];
    p.dwh   = d_in[15];
    p.db    = d_in[16];
    p.gw    = d_in[17];
    p.gb    = d_in[18];
    p.ws    = (float*)d_ws;
    p.out   = (float*)d_out;

    // zero barrier + recurrent state (carry0 = zeros)
    hipMemsetAsync(d_ws, 0, ZERO_BYTES, stream);

    void* args[] = {&p};
    hipError_t err = hipLaunchCooperativeKernel((void*)tts_decoder, dim3(NB), dim3(NT),
                                                args, 0, stream);
    if (err != hipSuccess) {
        tts_decoder<<<dim3(NB), dim3(NT), 0, stream>>>(p);
    }
}